// Round 11
// baseline (102.779 us; speedup 1.0000x reference)
//
#include <hip/hip_runtime.h>

// QuantizedConv2d int8 3x3, N=64, Cin=Cout=128, 56x56, pad=1 (value = input zp),
// int32 accum, per-channel requant. Harness widens integer arrays to int32
// (inputs AND output buffer).
//
// R11: occupancy-first conv. Wave = 1 M-tile x 4 N-tiles (acc 64 AGPR, VGPR
// ~60 -> ~125 unified regs/wave -> 16-wave/CU reg budget). ROWS=2 (xs 29.7KB),
// B = 4-deep x 4KB counted-vmcnt LDS pipeline (16KB). LDS 47.1KB -> 3
// blocks/CU = 3 waves/SIMD (vs 2 in R7-R9). Race ledger (same as R9):
//  - unit u reads Bb[u&3]; stage(u+3) goes to Bb[(u+3)&3]=(u-1)&3, issued
//    after barrier u (all waves finished compute u-1) -> no overwrite race.
//  - 1 gl16/wave/unit -> steady outstanding {u+1,u+2} at wait -> vmcnt(2)
//    retires unit-u's load; all waves wait before barrier u -> LDS complete.
//  - tail: u=33 vmcnt(2), u=34 vmcnt(1), u=35 vmcnt(0).
// Swizzle algebra / MFMA C/D map / epilogue verified since R7. repack_x /
// pack_w2 unchanged.

#define CIN  128
#define COUT 128
#define HW   56
#define NPIX (HW * HW)
#define ROWS  2
#define QCOLS 58
#define XROW  (QCOLS * CIN)          // 7424 B per padded row
#define XP_OFF 147456                // xp starts after wp2 in d_ws
#define XP_ROWS (64 * QCOLS)         // 3712

typedef int v4i  __attribute__((ext_vector_type(4)));
typedef int v16i __attribute__((ext_vector_type(16)));

__device__ __forceinline__ void gl16(const void* g, void* l) {
    __builtin_amdgcn_global_load_lds(
        (const __attribute__((address_space(1))) unsigned*)g,
        (__attribute__((address_space(3))) unsigned*)l, 16, 0, 0);
}

// ---- pack weights, swizzled (unchanged, verified) ----
// step = t*4+cb; in-chunk granule g = cout*2+(dw>>2); gs = g ^ ((g>>3)&7);
// chunk dword = gs*4 + (dw&3). byte b of dword dw -> ci = cb*32+dw*4+b, tap t.
__global__ __launch_bounds__(256) void pack_w2(const int* __restrict__ w_g,
                                               unsigned* __restrict__ wp2) {
    int i = blockIdx.x * 256 + threadIdx.x;
    if (i >= 36 * 128 * 8) return;
    int dw   = i & 7;
    int cout = (i >> 3) & 127;
    int step = i >> 10;
    int t  = step >> 2;
    int cb = step & 3;
    unsigned d = 0;
#pragma unroll
    for (int b = 0; b < 4; ++b) {
        int ci = cb * 32 + dw * 4 + b;
        int v = w_g[(cout * CIN + ci) * 9 + t];
        d |= (unsigned)(v & 0xFF) << (8 * b);
    }
    int g  = (cout << 1) | (dw >> 2);
    int gs = g ^ ((g >> 3) & 7);
    wp2[step * 1024 + gs * 4 + (dw & 3)] = d;
}

// ---- repack x: LDS transpose (unchanged, verified) ----
#define LSTR 57
__global__ __launch_bounds__(256) void repack_x(const int* __restrict__ x_g,
                                                unsigned char* __restrict__ xp,
                                                const int* __restrict__ zp_in_p) {
    __shared__ int lx[CIN * LSTR];
    const int blk = blockIdx.x;          // n*58 + hp
    const int n  = blk / QCOLS;
    const int hp = blk % QCOLS;
    const int tid = threadIdx.x;
    const unsigned zpd = (unsigned)((*zp_in_p) & 0xFF) * 0x01010101u;
    unsigned* row = (unsigned*)(xp + (size_t)blk * XROW);

    if (hp == 0 || hp == QCOLS - 1) {
#pragma unroll
        for (int it = 0; it < 8; ++it) {
            int d = it * 256 + tid;
            if (d < QCOLS * 32) row[d] = zpd;
        }
        return;
    }
    const int h = hp - 1;
    const int* xrow = x_g + (n * CIN * HW + h) * HW;
#pragma unroll
    for (int it = 0; it < 7; ++it) {
        int idx = it * 256 + tid;
        int ci  = idx / 14;
        int w4  = (idx - ci * 14) * 4;
        v4i L = *(const v4i*)(xrow + ci * NPIX + w4);
        int* ld = &lx[ci * LSTR + w4];
        ld[0] = L[0]; ld[1] = L[1]; ld[2] = L[2]; ld[3] = L[3];
    }
    __syncthreads();
#pragma unroll
    for (int it = 0; it < 8; ++it) {
        int d = it * 256 + tid;
        if (d < QCOLS * 32) {
            int wp  = d >> 5;
            int ci4 = d & 31;
            unsigned v = zpd;
            if (wp >= 1 && wp <= HW) {
                const int* lb = &lx[ci4 * 4 * LSTR + (wp - 1)];
                v = (unsigned)(lb[0] & 0xFF) |
                    ((unsigned)(lb[LSTR] & 0xFF) << 8) |
                    ((unsigned)(lb[2 * LSTR] & 0xFF) << 16) |
                    ((unsigned)(lb[3 * LSTR] & 0xFF) << 24);
            }
            row[d] = v;
        }
    }
}

// ---- conv: 1Mx4N waves, 3 blocks/CU, 4-deep counted-vmcnt B pipeline ----
__global__ __launch_bounds__(256, 3) void conv_mfma(
    const unsigned char* __restrict__ xp, const unsigned char* __restrict__ wp2b,
    const int* __restrict__ bias, const float* __restrict__ in_s,
    const float* __restrict__ w_s, const float* __restrict__ out_s,
    const int* __restrict__ zp_out_p, int* __restrict__ out) {
    __shared__ unsigned char xsb[29696];     // 29 x 1024B (232 q-rows), exact
    __shared__ unsigned char Bb[4][4096];    // 16KB: 4-deep B step pipeline
    __shared__ float scs[COUT];
    __shared__ int   bis[COUT];

    const int n   = blockIdx.x / 28;
    const int ho0 = (blockIdx.x % 28) * ROWS;
    const int tid    = threadIdx.x;
    const int lane   = tid & 63;
    const int wave   = tid >> 6;     // = M-tile index 0..3
    const int lane31 = lane & 31;
    const int hi     = lane >> 5;
    const int hi4    = hi * 4;

    if (tid < COUT) {
        scs[tid] = ((*in_s) / (*out_s)) * w_s[tid];
        bis[tid] = bias[tid];
    }

#define STAGEB(U)                                                             \
    gl16(wp2b + (U) * 4096 + tid * 16, &Bb[(U) & 3][wave * 1024]);

    // ---- prologue: B steps 0..2, then x window (4 padded rows, 29KB) ----
    STAGEB(0); STAGEB(1); STAGEB(2);
    const unsigned char* win = xp + (size_t)(n * QCOLS + ho0) * XROW;
    const int qrel = lane >> 3;
    const int lof  = (qrel * 8 + ((lane & 7) ^ qrel)) * 16;
    for (int i = wave; i < 29; i += 4)
        gl16(win + i * 1024 + lof, xsb + i * 1024);
    __syncthreads();   // drains all prologue VMEM; pipeline re-primes

    const unsigned* xs = (const unsigned*)xsb;
    const int px  = wave * 32 + lane31;
    const int pxc = px < ROWS * HW ? px : ROWS * HW - 1;   // wave3 half pad
    const int qb  = (pxc / HW) * QCOLS + (pxc % HW);
    int boff[4];
#pragma unroll
    for (int nt = 0; nt < 4; ++nt) {
        int g = nt * 64 + lane31 * 2 + hi;
        boff[nt] = (g ^ ((g >> 3) & 7)) * 16;
    }

    v16i acc[4];
#pragma unroll
    for (int j = 0; j < 4; ++j) acc[j] = (v16i)0;

#define COMPUTE(U)                                                            \
    {                                                                         \
        const int t  = (U) >> 2;                                              \
        const int kr = (t * 11) >> 5;                                         \
        const int dq = kr * QCOLS + (t - 3 * kr);                             \
        const int q  = qb + dq;                                               \
        const int sx = (q & 7) << 2;                                          \
        const int cb = (U) & 3;                                               \
        v4i a = *(const v4i*)&xs[q * 32 + ((cb * 8 + hi4) ^ sx)];             \
        const unsigned char* bb = Bb[(U) & 3];                                \
        v4i b0 = *(const v4i*)(bb + boff[0]);                                 \
        v4i b1 = *(const v4i*)(bb + boff[1]);                                 \
        v4i b2 = *(const v4i*)(bb + boff[2]);                                 \
        v4i b3 = *(const v4i*)(bb + boff[3]);                                 \
        __builtin_amdgcn_s_setprio(1);                                        \
        acc[0] = __builtin_amdgcn_mfma_i32_32x32x32_i8(b0, a, acc[0], 0, 0, 0); \
        acc[1] = __builtin_amdgcn_mfma_i32_32x32x32_i8(b1, a, acc[1], 0, 0, 0); \
        acc[2] = __builtin_amdgcn_mfma_i32_32x32x32_i8(b2, a, acc[2], 0, 0, 0); \
        acc[3] = __builtin_amdgcn_mfma_i32_32x32x32_i8(b3, a, acc[3], 0, 0, 0); \
        __builtin_amdgcn_s_setprio(0);                                        \
    }

    // ---- main loop: units 0..32 stage u+3; tail 33/34/35 peeled ----
#pragma unroll 1
    for (int u = 0; u < 33; ++u) {
        asm volatile("s_waitcnt vmcnt(2)" ::: "memory");
        __builtin_amdgcn_sched_barrier(0);
        __builtin_amdgcn_s_barrier();
        asm volatile("" ::: "memory");
        STAGEB(u + 3);
        COMPUTE(u);
    }
    asm volatile("s_waitcnt vmcnt(2)" ::: "memory");
    __builtin_amdgcn_sched_barrier(0);
    __builtin_amdgcn_s_barrier();
    COMPUTE(33);
    asm volatile("s_waitcnt vmcnt(1)" ::: "memory");
    __builtin_amdgcn_sched_barrier(0);
    __builtin_amdgcn_s_barrier();
    COMPUTE(34);
    asm volatile("s_waitcnt vmcnt(0)" ::: "memory");
    __builtin_amdgcn_sched_barrier(0);
    __builtin_amdgcn_s_barrier();
    COMPUTE(35);
#undef COMPUTE
#undef STAGEB

    // ---- epilogue: co = nt*32 + (reg&3)+8*(reg>>2)+hi4 ; col = px ----
    const float zpo = (float)(*zp_out_p);
    if (px < ROWS * HW) {
        int* ob = out + n * COUT * NPIX + ho0 * HW + px;
#pragma unroll
        for (int nt = 0; nt < 4; ++nt) {
#pragma unroll
            for (int reg = 0; reg < 16; ++reg) {
                int co = nt * 32 + (reg & 3) + 8 * (reg >> 2) + hi4;
                float f = fmaf((float)(acc[nt][reg] + bis[co]), scs[co], zpo);
                f = rintf(f);
                f = fminf(fmaxf(f, -128.0f), 127.0f);
                ob[co * NPIX] = (int)f;
            }
        }
    }
}

extern "C" void kernel_launch(void* const* d_in, const int* in_sizes, int n_in,
                              void* d_out, int out_size, void* d_ws, size_t ws_size,
                              hipStream_t stream) {
    const int* x_g      = (const int*)d_in[0];
    const int* w_g      = (const int*)d_in[1];
    const int* bias     = (const int*)d_in[2];
    const float* in_s   = (const float*)d_in[3];
    const float* w_s    = (const float*)d_in[4];
    const float* out_s  = (const float*)d_in[5];
    const int* zp_in_p  = (const int*)d_in[6];
    const int* zp_out_p = (const int*)d_in[7];
    int* outp = (int*)d_out;
    unsigned* wp2 = (unsigned*)d_ws;                           // 147456 B
    unsigned char* xpp = (unsigned char*)d_ws + XP_OFF;        // 27,557,888 B

    pack_w2<<<(36 * 128 * 8 + 255) / 256, 256, 0, stream>>>(w_g, wp2);
    repack_x<<<XP_ROWS, 256, 0, stream>>>(x_g, xpp, zp_in_p);

    const int nblocks = 64 * (HW / ROWS);   // 1792
    conv_mfma<<<nblocks, 256, 0, stream>>>(xpp, (const unsigned char*)wp2, bias,
                                           in_s, w_s, out_s, zp_out_p, outp);
}

// Round 12
// 88.916 us; speedup vs baseline: 1.1559x; 1.1559x over previous
//
#include <hip/hip_runtime.h>

// QuantizedConv2d int8 3x3, N=64, Cin=Cout=128, 56x56, pad=1 (value = input zp),
// int32 accum, per-channel requant. Harness widens integer arrays to int32
// (inputs AND output buffer).
//
// R12: barrier-free, occupancy-4 conv. Wave = 1 M-tile x 4 N-tiles (acc 64
// AGPR). A (x) staged once to LDS (29.7KB, gl16 pre-swizzled source, R11-
// verified). B (weights) loaded global->registers per step, 2-deep static
// rotation (R8-verified addressing; SGPR base + 32-bit offsets), L1/L2-hot.
// ZERO barriers after x staging; __launch_bounds__(256,4) binds regs <=128
// unified -> 4 waves/SIMD, waves drift anti-phase. Epilogue: bias folded into
// ofs = bias*sc + zpo (single fmaf), min/max clamp.
// repack_x / pack_w2 unchanged (verified R7+).

#define CIN  128
#define COUT 128
#define HW   56
#define NPIX (HW * HW)
#define ROWS  2
#define QCOLS 58
#define XROW  (QCOLS * CIN)          // 7424 B per padded row
#define XP_OFF 147456                // xp starts after wp2 in d_ws
#define XP_ROWS (64 * QCOLS)         // 3712

typedef int v4i  __attribute__((ext_vector_type(4)));
typedef int v16i __attribute__((ext_vector_type(16)));

__device__ __forceinline__ void gl16(const void* g, void* l) {
    __builtin_amdgcn_global_load_lds(
        (const __attribute__((address_space(1))) unsigned*)g,
        (__attribute__((address_space(3))) unsigned*)l, 16, 0, 0);
}

// ---- pack weights, swizzled (unchanged, verified) ----
// step = t*4+cb; in-chunk granule g = cout*2+(dw>>2); gs = g ^ ((g>>3)&7);
// chunk dword = gs*4 + (dw&3). byte b of dword dw -> ci = cb*32+dw*4+b, tap t.
__global__ __launch_bounds__(256) void pack_w2(const int* __restrict__ w_g,
                                               unsigned* __restrict__ wp2) {
    int i = blockIdx.x * 256 + threadIdx.x;
    if (i >= 36 * 128 * 8) return;
    int dw   = i & 7;
    int cout = (i >> 3) & 127;
    int step = i >> 10;
    int t  = step >> 2;
    int cb = step & 3;
    unsigned d = 0;
#pragma unroll
    for (int b = 0; b < 4; ++b) {
        int ci = cb * 32 + dw * 4 + b;
        int v = w_g[(cout * CIN + ci) * 9 + t];
        d |= (unsigned)(v & 0xFF) << (8 * b);
    }
    int g  = (cout << 1) | (dw >> 2);
    int gs = g ^ ((g >> 3) & 7);
    wp2[step * 1024 + gs * 4 + (dw & 3)] = d;
}

// ---- repack x: LDS transpose (unchanged, verified) ----
#define LSTR 57
__global__ __launch_bounds__(256) void repack_x(const int* __restrict__ x_g,
                                                unsigned char* __restrict__ xp,
                                                const int* __restrict__ zp_in_p) {
    __shared__ int lx[CIN * LSTR];
    const int blk = blockIdx.x;          // n*58 + hp
    const int n  = blk / QCOLS;
    const int hp = blk % QCOLS;
    const int tid = threadIdx.x;
    const unsigned zpd = (unsigned)((*zp_in_p) & 0xFF) * 0x01010101u;
    unsigned* row = (unsigned*)(xp + (size_t)blk * XROW);

    if (hp == 0 || hp == QCOLS - 1) {
#pragma unroll
        for (int it = 0; it < 8; ++it) {
            int d = it * 256 + tid;
            if (d < QCOLS * 32) row[d] = zpd;
        }
        return;
    }
    const int h = hp - 1;
    const int* xrow = x_g + (n * CIN * HW + h) * HW;
#pragma unroll
    for (int it = 0; it < 7; ++it) {
        int idx = it * 256 + tid;
        int ci  = idx / 14;
        int w4  = (idx - ci * 14) * 4;
        v4i L = *(const v4i*)(xrow + ci * NPIX + w4);
        int* ld = &lx[ci * LSTR + w4];
        ld[0] = L[0]; ld[1] = L[1]; ld[2] = L[2]; ld[3] = L[3];
    }
    __syncthreads();
#pragma unroll
    for (int it = 0; it < 8; ++it) {
        int d = it * 256 + tid;
        if (d < QCOLS * 32) {
            int wp  = d >> 5;
            int ci4 = d & 31;
            unsigned v = zpd;
            if (wp >= 1 && wp <= HW) {
                const int* lb = &lx[ci4 * 4 * LSTR + (wp - 1)];
                v = (unsigned)(lb[0] & 0xFF) |
                    ((unsigned)(lb[LSTR] & 0xFF) << 8) |
                    ((unsigned)(lb[2 * LSTR] & 0xFF) << 16) |
                    ((unsigned)(lb[3 * LSTR] & 0xFF) << 24);
            }
            row[d] = v;
        }
    }
}

// ---- conv: 1Mx4N waves, barrier-free, B in registers, 4 waves/SIMD ----
__global__ __launch_bounds__(256, 4) void conv_mfma(
    const unsigned char* __restrict__ xp, const unsigned char* __restrict__ wp2b,
    const int* __restrict__ bias, const float* __restrict__ in_s,
    const float* __restrict__ w_s, const float* __restrict__ out_s,
    const int* __restrict__ zp_out_p, int* __restrict__ out) {
    __shared__ unsigned char xsb[29696];     // 29 x 1024B = 232 q-rows, exact
    __shared__ float scs[COUT];
    __shared__ float ofs[COUT];              // bias*sc + zpo folded

    const int n   = blockIdx.x / 28;
    const int ho0 = (blockIdx.x % 28) * ROWS;
    const int tid    = threadIdx.x;
    const int lane   = tid & 63;
    const int wave   = tid >> 6;     // = M-tile index 0..3
    const int lane31 = lane & 31;
    const int hi     = lane >> 5;
    const int hi4    = hi * 4;

    if (tid < COUT) {
        float sc = ((*in_s) / (*out_s)) * w_s[tid];
        scs[tid] = sc;
        ofs[tid] = (float)bias[tid] * sc + (float)(*zp_out_p);
    }

    // ---- stage x window: 4 padded rows = 29696 contiguous bytes ----
    const unsigned char* win = xp + (size_t)(n * QCOLS + ho0) * XROW;
    const int qrel = lane >> 3;
    const int lof  = (qrel * 8 + ((lane & 7) ^ qrel)) * 16;
    for (int i = wave; i < 29; i += 4)
        gl16(win + i * 1024 + lof, xsb + i * 1024);
    __syncthreads();   // the ONLY barrier

    const unsigned* xs = (const unsigned*)xsb;
    const int px  = wave * 32 + lane31;
    const int pxc = px < ROWS * HW ? px : ROWS * HW - 1;   // wave3 half pad
    const int qb  = (pxc / HW) * QCOLS + (pxc % HW);
    // B offsets (32-bit, SGPR-base loads); step s adds s*4096
    int bo0, bo1, bo2, bo3;
    {
        int g0 = 0 * 64 + lane31 * 2 + hi;
        int g1 = 1 * 64 + lane31 * 2 + hi;
        int g2 = 2 * 64 + lane31 * 2 + hi;
        int g3 = 3 * 64 + lane31 * 2 + hi;
        bo0 = (g0 ^ ((g0 >> 3) & 7)) * 16;
        bo1 = (g1 ^ ((g1 >> 3) & 7)) * 16;
        bo2 = (g2 ^ ((g2 >> 3) & 7)) * 16;
        bo3 = (g3 ^ ((g3 >> 3) & 7)) * 16;
    }

    v16i acc0 = (v16i)0, acc1 = (v16i)0, acc2 = (v16i)0, acc3 = (v16i)0;

#define LOADB(B0, B1, B2, B3, S)                                             \
    {                                                                        \
        const int so = (S) * 4096;                                           \
        B0 = *(const v4i*)(wp2b + so + bo0);                                 \
        B1 = *(const v4i*)(wp2b + so + bo1);                                 \
        B2 = *(const v4i*)(wp2b + so + bo2);                                 \
        B3 = *(const v4i*)(wp2b + so + bo3);                                 \
    }
#define LDA(AF, S)                                                           \
    {                                                                        \
        const int t  = (S) >> 2;                                             \
        const int kr = (t * 11) >> 5;                                        \
        const int q  = qb + kr * QCOLS + (t - 3 * kr);                       \
        const int cb = (S) & 3;                                              \
        AF = *(const v4i*)&xs[q * 32 + ((cb * 8 + hi4) ^ ((q & 7) << 2))];   \
    }
#define FIRE(AF, B0, B1, B2, B3)                                             \
    {                                                                        \
        acc0 = __builtin_amdgcn_mfma_i32_32x32x32_i8(B0, AF, acc0, 0, 0, 0); \
        acc1 = __builtin_amdgcn_mfma_i32_32x32x32_i8(B1, AF, acc1, 0, 0, 0); \
        acc2 = __builtin_amdgcn_mfma_i32_32x32x32_i8(B2, AF, acc2, 0, 0, 0); \
        acc3 = __builtin_amdgcn_mfma_i32_32x32x32_i8(B3, AF, acc3, 0, 0, 0); \
    }

    v4i aA, aB, bA0, bA1, bA2, bA3, bB0, bB1, bB2, bB3;
    LOADB(bA0, bA1, bA2, bA3, 0); LDA(aA, 0);
    LOADB(bB0, bB1, bB2, bB3, 1); LDA(aB, 1);
#pragma unroll 1
    for (int ss = 0; ss < 36; ss += 2) {
        FIRE(aA, bA0, bA1, bA2, bA3);
        if (ss + 2 < 36) { LOADB(bA0, bA1, bA2, bA3, ss + 2); LDA(aA, ss + 2); }
        FIRE(aB, bB0, bB1, bB2, bB3);
        if (ss + 3 < 36) { LOADB(bB0, bB1, bB2, bB3, ss + 3); LDA(aB, ss + 3); }
    }
#undef FIRE
#undef LDA
#undef LOADB

    // ---- epilogue: co = nt*32 + (reg&3)+8*(reg>>2)+hi4 ; col = px ----
    if (px < ROWS * HW) {
        int* ob = out + n * COUT * NPIX + ho0 * HW + px;
        const v16i* accs[1];  // avoid runtime-indexed array; unroll by name
#pragma unroll
        for (int nt = 0; nt < 4; ++nt) {
            const v16i& A = (nt == 0) ? acc0 : (nt == 1) ? acc1 : (nt == 2) ? acc2 : acc3;
#pragma unroll
            for (int reg = 0; reg < 16; ++reg) {
                int co = nt * 32 + (reg & 3) + 8 * (reg >> 2) + hi4;
                float f = fmaf((float)A[reg], scs[co], ofs[co]);
                f = rintf(f);
                f = fminf(fmaxf(f, -128.0f), 127.0f);
                ob[co * NPIX] = (int)f;
            }
        }
        (void)accs;
    }
}

extern "C" void kernel_launch(void* const* d_in, const int* in_sizes, int n_in,
                              void* d_out, int out_size, void* d_ws, size_t ws_size,
                              hipStream_t stream) {
    const int* x_g      = (const int*)d_in[0];
    const int* w_g      = (const int*)d_in[1];
    const int* bias     = (const int*)d_in[2];
    const float* in_s   = (const float*)d_in[3];
    const float* w_s    = (const float*)d_in[4];
    const float* out_s  = (const float*)d_in[5];
    const int* zp_in_p  = (const int*)d_in[6];
    const int* zp_out_p = (const int*)d_in[7];
    int* outp = (int*)d_out;
    unsigned* wp2 = (unsigned*)d_ws;                           // 147456 B
    unsigned char* xpp = (unsigned char*)d_ws + XP_OFF;        // 27,557,888 B

    pack_w2<<<(36 * 128 * 8 + 255) / 256, 256, 0, stream>>>(w_g, wp2);
    repack_x<<<XP_ROWS, 256, 0, stream>>>(x_g, xpp, zp_in_p);

    const int nblocks = 64 * (HW / ROWS);   // 1792
    conv_mfma<<<nblocks, 256, 0, stream>>>(xpp, (const unsigned char*)wp2, bias,
                                           in_s, w_s, out_s, zp_out_p, outp);
}

// Round 13
// 84.051 us; speedup vs baseline: 1.2228x; 1.0579x over previous
//
#include <hip/hip_runtime.h>

// QuantizedConv2d int8 3x3, N=64, Cin=Cout=128, 56x56, pad=1 (value = input zp),
// int32 accum, per-channel requant. Harness widens integer arrays to int32
// (inputs AND output buffer).
//
// R13: 8-wave (512thr) blocks, ROWS=4. Wave = 2 M-tiles x 2 N-tiles:
// per step {2 B global->reg loads + 2 A ds_reads -> 4 MFMA}, 2-deep prefetch,
// zero K-loop barriers. Per-wave B = 73KB (total L2 B-traffic 527MB, ~half of
// R12). acc 64 AGPR + ~60 VGPR <= 128 -> launch_bounds(512,4) = 4 waves/SIMD
// (2 independent blocks/CU). 7 M-tiles over 8 slots; slot 8 clamped+store-
// guarded. All swizzle / MFMA C-D / epilogue algebra verified since R7.
// repack_x / pack_w2 unchanged.

#define CIN  128
#define COUT 128
#define HW   56
#define NPIX (HW * HW)
#define ROWS  4
#define QCOLS 58
#define XROW  (QCOLS * CIN)          // 7424 B per padded row
#define XP_OFF 147456                // xp starts after wp2 in d_ws
#define XP_ROWS (64 * QCOLS)         // 3712

typedef int v4i  __attribute__((ext_vector_type(4)));
typedef int v16i __attribute__((ext_vector_type(16)));

__device__ __forceinline__ void gl16(const void* g, void* l) {
    __builtin_amdgcn_global_load_lds(
        (const __attribute__((address_space(1))) unsigned*)g,
        (__attribute__((address_space(3))) unsigned*)l, 16, 0, 0);
}

// ---- pack weights, swizzled (unchanged, verified) ----
// step = t*4+cb; in-chunk granule g = cout*2+(dw>>2); gs = g ^ ((g>>3)&7);
// chunk dword = gs*4 + (dw&3). byte b of dword dw -> ci = cb*32+dw*4+b, tap t.
__global__ __launch_bounds__(256) void pack_w2(const int* __restrict__ w_g,
                                               unsigned* __restrict__ wp2) {
    int i = blockIdx.x * 256 + threadIdx.x;
    if (i >= 36 * 128 * 8) return;
    int dw   = i & 7;
    int cout = (i >> 3) & 127;
    int step = i >> 10;
    int t  = step >> 2;
    int cb = step & 3;
    unsigned d = 0;
#pragma unroll
    for (int b = 0; b < 4; ++b) {
        int ci = cb * 32 + dw * 4 + b;
        int v = w_g[(cout * CIN + ci) * 9 + t];
        d |= (unsigned)(v & 0xFF) << (8 * b);
    }
    int g  = (cout << 1) | (dw >> 2);
    int gs = g ^ ((g >> 3) & 7);
    wp2[step * 1024 + gs * 4 + (dw & 3)] = d;
}

// ---- repack x: LDS transpose (unchanged, verified) ----
#define LSTR 57
__global__ __launch_bounds__(256) void repack_x(const int* __restrict__ x_g,
                                                unsigned char* __restrict__ xp,
                                                const int* __restrict__ zp_in_p) {
    __shared__ int lx[CIN * LSTR];
    const int blk = blockIdx.x;          // n*58 + hp
    const int n  = blk / QCOLS;
    const int hp = blk % QCOLS;
    const int tid = threadIdx.x;
    const unsigned zpd = (unsigned)((*zp_in_p) & 0xFF) * 0x01010101u;
    unsigned* row = (unsigned*)(xp + (size_t)blk * XROW);

    if (hp == 0 || hp == QCOLS - 1) {
#pragma unroll
        for (int it = 0; it < 8; ++it) {
            int d = it * 256 + tid;
            if (d < QCOLS * 32) row[d] = zpd;
        }
        return;
    }
    const int h = hp - 1;
    const int* xrow = x_g + (n * CIN * HW + h) * HW;
#pragma unroll
    for (int it = 0; it < 7; ++it) {
        int idx = it * 256 + tid;
        int ci  = idx / 14;
        int w4  = (idx - ci * 14) * 4;
        v4i L = *(const v4i*)(xrow + ci * NPIX + w4);
        int* ld = &lx[ci * LSTR + w4];
        ld[0] = L[0]; ld[1] = L[1]; ld[2] = L[2]; ld[3] = L[3];
    }
    __syncthreads();
#pragma unroll
    for (int it = 0; it < 8; ++it) {
        int d = it * 256 + tid;
        if (d < QCOLS * 32) {
            int wp  = d >> 5;
            int ci4 = d & 31;
            unsigned v = zpd;
            if (wp >= 1 && wp <= HW) {
                const int* lb = &lx[ci4 * 4 * LSTR + (wp - 1)];
                v = (unsigned)(lb[0] & 0xFF) |
                    ((unsigned)(lb[LSTR] & 0xFF) << 8) |
                    ((unsigned)(lb[2 * LSTR] & 0xFF) << 16) |
                    ((unsigned)(lb[3 * LSTR] & 0xFF) << 24);
            }
            row[d] = v;
        }
    }
}

// ---- conv: 8 waves, 2Mx2N per wave, B in regs, barrier-free K-loop ----
__global__ __launch_bounds__(512, 4) void conv_mfma(
    const unsigned char* __restrict__ xp, const unsigned char* __restrict__ wp2b,
    const int* __restrict__ bias, const float* __restrict__ in_s,
    const float* __restrict__ w_s, const float* __restrict__ out_s,
    const int* __restrict__ zp_out_p, int* __restrict__ out) {
    __shared__ unsigned char xsb[45056];     // 44 x 1024B (348 q-rows used)
    __shared__ float scs[COUT];
    __shared__ float ofs[COUT];              // bias*sc + zpo folded

    const int n   = blockIdx.x / 14;
    const int ho0 = (blockIdx.x % 14) * ROWS;
    const int tid    = threadIdx.x;
    const int lane   = tid & 63;
    const int wave   = tid >> 6;     // 0..7
    const int mp     = wave & 3;     // M-pair: tiles {2mp, 2mp+1}
    const int np     = wave >> 2;    // N-pair: tiles {2np, 2np+1}
    const int lane31 = lane & 31;
    const int hi     = lane >> 5;
    const int hi4    = hi * 4;

    if (tid < COUT) {
        float sc = ((*in_s) / (*out_s)) * w_s[tid];
        scs[tid] = sc;
        ofs[tid] = (float)bias[tid] * sc + (float)(*zp_out_p);
    }

    // ---- stage x window: 6 padded rows = 44544 contiguous bytes ----
    const unsigned char* win = xp + (size_t)(n * QCOLS + ho0) * XROW;
    const int qrel = lane >> 3;
    const int lof  = (qrel * 8 + ((lane & 7) ^ qrel)) * 16;
    for (int i = wave; i < 44; i += 8) {
        int off = i * 1024 + lof;
        if (i == 43 && qrel >= 4) off = 0;           // q-rows 348+ unused
        gl16(win + off, xsb + i * 1024);
    }
    __syncthreads();   // the ONLY barrier

    const unsigned* xs = (const unsigned*)xsb;
    const int px0 = mp * 64 + lane31;                 // tile 2mp
    const int px1 = mp * 64 + 32 + lane31;            // tile 2mp+1 (mp=3: pad)
    const int px1c = px1 < ROWS * HW ? px1 : ROWS * HW - 1;
    const int qb0 = (px0 / HW) * QCOLS + (px0 % HW);
    const int qb1 = (px1c / HW) * QCOLS + (px1c % HW);
    int bo0, bo1;
    {
        int g0 = (np * 2 + 0) * 64 + lane31 * 2 + hi;
        int g1 = (np * 2 + 1) * 64 + lane31 * 2 + hi;
        bo0 = (g0 ^ ((g0 >> 3) & 7)) * 16;
        bo1 = (g1 ^ ((g1 >> 3) & 7)) * 16;
    }

    v16i acc00 = (v16i)0, acc01 = (v16i)0, acc10 = (v16i)0, acc11 = (v16i)0;

#define LOADB(B0, B1, S)                                                     \
    {                                                                        \
        const int so = (S) * 4096;                                           \
        B0 = *(const v4i*)(wp2b + so + bo0);                                 \
        B1 = *(const v4i*)(wp2b + so + bo1);                                 \
    }
#define LDA(A0, A1, S)                                                       \
    {                                                                        \
        const int t  = (S) >> 2;                                             \
        const int kr = (t * 11) >> 5;                                        \
        const int dq = kr * QCOLS + (t - 3 * kr);                            \
        const int q0 = qb0 + dq, q1 = qb1 + dq;                              \
        const int cb = (S) & 3;                                              \
        A0 = *(const v4i*)&xs[q0 * 32 + ((cb * 8 + hi4) ^ ((q0 & 7) << 2))]; \
        A1 = *(const v4i*)&xs[q1 * 32 + ((cb * 8 + hi4) ^ ((q1 & 7) << 2))]; \
    }
#define FIRE(A0, A1, B0, B1)                                                 \
    {                                                                        \
        acc00 = __builtin_amdgcn_mfma_i32_32x32x32_i8(B0, A0, acc00, 0, 0, 0); \
        acc01 = __builtin_amdgcn_mfma_i32_32x32x32_i8(B1, A0, acc01, 0, 0, 0); \
        acc10 = __builtin_amdgcn_mfma_i32_32x32x32_i8(B0, A1, acc10, 0, 0, 0); \
        acc11 = __builtin_amdgcn_mfma_i32_32x32x32_i8(B1, A1, acc11, 0, 0, 0); \
    }

    v4i aA0, aA1, aB0, aB1, bA0, bA1, bB0, bB1;
    LOADB(bA0, bA1, 0); LDA(aA0, aA1, 0);
    LOADB(bB0, bB1, 1); LDA(aB0, aB1, 1);
#pragma unroll 1
    for (int ss = 0; ss < 36; ss += 2) {
        FIRE(aA0, aA1, bA0, bA1);
        if (ss + 2 < 36) { LOADB(bA0, bA1, ss + 2); LDA(aA0, aA1, ss + 2); }
        FIRE(aB0, aB1, bB0, bB1);
        if (ss + 3 < 36) { LOADB(bB0, bB1, ss + 3); LDA(aB0, aB1, ss + 3); }
    }
#undef FIRE
#undef LDA
#undef LOADB

    // ---- epilogue: co = nt*32 + (reg&3)+8*(reg>>2)+hi4 ; col = px ----
    const int obase = n * COUT * NPIX + ho0 * HW;
#pragma unroll
    for (int mi = 0; mi < 2; ++mi) {
        const int px = mp * 64 + mi * 32 + lane31;
        if (px < ROWS * HW) {
            int* ob = out + obase + px;
#pragma unroll
            for (int ni = 0; ni < 2; ++ni) {
                const v16i& A = (mi == 0) ? (ni == 0 ? acc00 : acc01)
                                          : (ni == 0 ? acc10 : acc11);
                const int ntb = (np * 2 + ni) * 32;
#pragma unroll
                for (int reg = 0; reg < 16; ++reg) {
                    int co = ntb + (reg & 3) + 8 * (reg >> 2) + hi4;
                    float f = fmaf((float)A[reg], scs[co], ofs[co]);
                    f = rintf(f);
                    f = fminf(fmaxf(f, -128.0f), 127.0f);
                    ob[co * NPIX] = (int)f;
                }
            }
        }
    }
}

extern "C" void kernel_launch(void* const* d_in, const int* in_sizes, int n_in,
                              void* d_out, int out_size, void* d_ws, size_t ws_size,
                              hipStream_t stream) {
    const int* x_g      = (const int*)d_in[0];
    const int* w_g      = (const int*)d_in[1];
    const int* bias     = (const int*)d_in[2];
    const float* in_s   = (const float*)d_in[3];
    const float* w_s    = (const float*)d_in[4];
    const float* out_s  = (const float*)d_in[5];
    const int* zp_in_p  = (const int*)d_in[6];
    const int* zp_out_p = (const int*)d_in[7];
    int* outp = (int*)d_out;
    unsigned* wp2 = (unsigned*)d_ws;                           // 147456 B
    unsigned char* xpp = (unsigned char*)d_ws + XP_OFF;        // 27,557,888 B

    pack_w2<<<(36 * 128 * 8 + 255) / 256, 256, 0, stream>>>(w_g, wp2);
    repack_x<<<XP_ROWS, 256, 0, stream>>>(x_g, xpp, zp_in_p);

    const int nblocks = 64 * (HW / ROWS);   // 896
    conv_mfma<<<nblocks, 512, 0, stream>>>(xpp, (const unsigned char*)wp2, bias,
                                           in_s, w_s, out_s, zp_out_p, outp);
}